// Round 9
// baseline (234.874 us; speedup 1.0000x reference)
//
#include <hip/hip_runtime.h>
#include <hip/hip_bf16.h>

typedef __bf16 bf16x8 __attribute__((ext_vector_type(8)));
typedef float f32x4 __attribute__((ext_vector_type(4)));
typedef unsigned short u16;
typedef u16 u16x4 __attribute__((ext_vector_type(4)));
typedef u16 u16x8 __attribute__((ext_vector_type(8)));
typedef short s16x4 __attribute__((ext_vector_type(4)));

#define LDA 72  // padded stride for P / transpose LDS tiles

__device__ inline u16 f2bf(float f) {
    union { float f; unsigned u; } v; v.f = f;
    unsigned r = v.u + 0x7fffu + ((v.u >> 16) & 1u);
    return (u16)(r >> 16);
}

// async global->LDS, 16B per lane; LDS dst = wave-uniform base + lane*16
#define GLD16(g, l) __builtin_amdgcn_global_load_lds( \
    (const __attribute__((address_space(1))) unsigned int*)(g), \
    (__attribute__((address_space(3))) unsigned int*)(l), 16, 0, 0)

// ---------------- prep: X convert + weight transposes ----------------
// blocks [0,4096): X fp32->bf16; [4096,4864): Wk/Wq/Wv; [4864,5120): Wo.
__global__ void k_prep(const float* __restrict__ X, u16* __restrict__ Xb,
                       const float* __restrict__ Wk, const float* __restrict__ Wq,
                       const float* __restrict__ Wv, u16* __restrict__ WT,
                       const float* __restrict__ Wo, u16* __restrict__ WoT) {
    __shared__ u16 Ls[64 * LDA];
    int u = blockIdx.x, tid = threadIdx.x;
    if (u < 4096) {
        int idx = u * 256 + tid;
        float4 v = *(const float4*)&X[(size_t)idx * 4];
        u16x4 o; o.x = f2bf(v.x); o.y = f2bf(v.y); o.z = f2bf(v.z); o.w = f2bf(v.w);
        *(u16x4*)&Xb[(size_t)idx * 4] = o;
    } else if (u < 4864) {
        int b2 = u - 4096;
        int dt = b2 & 15, h = (b2 >> 4) & 15, p = b2 >> 8;
        const float* src = (p == 0 ? Wk : p == 1 ? Wq : Wv);
        int r0 = tid >> 4, c4 = tid & 15;
        for (int j = 0; j < 4; j++) {
            int d = r0 + j * 16;
            float4 v = *(const float4*)&src[((size_t)h * 1024 + dt * 64 + d) * 64 + c4 * 4];
            u16* q = &Ls[d * LDA + c4 * 4];
            q[0] = f2bf(v.x); q[1] = f2bf(v.y); q[2] = f2bf(v.z); q[3] = f2bf(v.w);
        }
        __syncthreads();
        int nk = tid >> 2, cd = tid & 3;
        u16 tmp[16];
        for (int j = 0; j < 16; j++) tmp[j] = Ls[(cd * 16 + j) * LDA + nk];
        size_t o = ((size_t)(p * 1024 + h * 64 + nk)) * 1024 + dt * 64 + cd * 16;
        *(u16x8*)&WT[o] = *(u16x8*)&tmp[0];
        *(u16x8*)&WT[o + 8] = *(u16x8*)&tmp[8];
    } else {
        int b2 = u - 4864;
        int dt = b2 & 15, nt2 = b2 >> 4;
        int r0 = tid >> 4, c4 = tid & 15;
        for (int j = 0; j < 4; j++) {
            int d = r0 + j * 16;
            float4 v = *(const float4*)&Wo[(size_t)(dt * 64 + d) * 1024 + nt2 * 64 + c4 * 4];
            u16* q = &Ls[d * LDA + c4 * 4];
            q[0] = f2bf(v.x); q[1] = f2bf(v.y); q[2] = f2bf(v.z); q[3] = f2bf(v.w);
        }
        __syncthreads();
        int nr = tid >> 2, cd = tid & 3;
        u16 tmp[16];
        for (int j = 0; j < 16; j++) tmp[j] = Ls[(cd * 16 + j) * LDA + nr];
        size_t o = ((size_t)(nt2 * 64 + nr)) * 1024 + dt * 64 + cd * 16;
        *(u16x8*)&WoT[o] = *(u16x8*)&tmp[0];
        *(u16x8*)&WoT[o + 8] = *(u16x8*)&tmp[8];
    }
}

// ---------------- fused QKV GEMM: C[4096 m][3072 n], K=1024 ----------------
// R9: LDS-FREE direct-from-global fragment loads. All operands are
// L2/L3-resident (logical 390MB vs 33MB HBM FETCH), so LDS staging only
// added the barrier+vmcnt(0)+ds_read serial path that R1/R5/R8 proved
// invariant at ~600 TF (waves/prefetch/partition all neutral). Each wave
// streams its 64x64 tile's fragments straight from L2: no __syncthreads,
// no GLD16, no ds_read. Redundancy 2x(A)+2x(B) ~= 770MB L2 reads, covered
// by 34.5 TB/s aggregate; 12 barrier-free waves/CU + 8 loads in flight
// hide L2 latency. Fragment math + epilogue identical to R1 (verified).
// grid (32 m-tiles, 24 n-slices), 4 waves 2x2, 256 threads.
__global__ __launch_bounds__(256) void k_qkv(
    const u16* __restrict__ Xb, const u16* __restrict__ WT,
    const float* __restrict__ bk, const float* __restrict__ bq, const float* __restrict__ bv,
    u16* __restrict__ Kw, u16* __restrict__ Qw, u16* __restrict__ Vtw)
{
    int tid = threadIdx.x, w = tid >> 6, lane = tid & 63, quad = lane >> 4, l16 = lane & 15;
    int wm = w & 1, wn = w >> 1;
    int m0 = blockIdx.x * 128, n0 = blockIdx.y * 128;

    int hb = blockIdx.y * 2 + wn;
    int p = hb >> 4, hh = hb & 15;
    bool ct = (p < 2);                        // wave-uniform: K/Q -> transposed acc

    // lane's fragment row pointers: row = m0+wm*64+mt*16+l16 (A), n0+wn*64+nt*16+l16 (B)
    const u16* Ap = Xb + (size_t)(m0 + wm * 64 + l16) * 1024 + quad * 8;
    const u16* Bp = WT + (size_t)(n0 + wn * 64 + l16) * 1024 + quad * 8;

    f32x4 acc[4][4] = {};
    #pragma unroll 1
    for (int k0 = 0; k0 < 1024; k0 += 64) {
        #pragma unroll
        for (int ks = 0; ks < 2; ks++) {
            bf16x8 af[4], bf[4];
            int kc = k0 + ks * 32;            // + quad*8 already in Ap/Bp
            #pragma unroll
            for (int mt = 0; mt < 4; mt++)
                af[mt] = *(const bf16x8*)&Ap[(size_t)mt * 16384 + kc];
            #pragma unroll
            for (int nt = 0; nt < 4; nt++)
                bf[nt] = *(const bf16x8*)&Bp[(size_t)nt * 16384 + kc];
            if (ct) {
                #pragma unroll
                for (int mt = 0; mt < 4; mt++)
                    #pragma unroll
                    for (int nt = 0; nt < 4; nt++)
                        acc[mt][nt] = __builtin_amdgcn_mfma_f32_16x16x32_bf16(bf[nt], af[mt], acc[mt][nt], 0, 0, 0);
            } else {
                #pragma unroll
                for (int mt = 0; mt < 4; mt++)
                    #pragma unroll
                    for (int nt = 0; nt < 4; nt++)
                        acc[mt][nt] = __builtin_amdgcn_mfma_f32_16x16x32_bf16(af[mt], bf[nt], acc[mt][nt], 0, 0, 0);
            }
        }
    }
    const float* bias = (p == 0 ? bk : p == 1 ? bq : bv) + hh * 64;
    if (ct) {
        // acc[mt][nt][r] = C[m = m0+wm*64+mt*16+l16][nk = nt*16+quad*4+r]
        u16* dst = (p == 0) ? Kw : Qw;
        float sc = (p == 0) ? 0.125f : 1.0f;   // fold 1/sqrt(64) into K
        for (int mt = 0; mt < 4; mt++) {
            int m = m0 + wm * 64 + mt * 16 + l16;
            int b = m >> 10, s = m & 1023;
            size_t base = ((size_t)((b << 4) + hh) * 1024 + s) * 64;
            for (int nt = 0; nt < 4; nt++) {
                float4 bb = *(const float4*)&bias[nt * 16 + quad * 4];
                u16x4 o;
                o[0] = f2bf((acc[mt][nt][0] + bb.x) * sc);
                o[1] = f2bf((acc[mt][nt][1] + bb.y) * sc);
                o[2] = f2bf((acc[mt][nt][2] + bb.z) * sc);
                o[3] = f2bf((acc[mt][nt][3] + bb.w) * sc);
                *(u16x4*)&dst[base + nt * 16 + quad * 4] = o;
            }
        }
    } else {
        // V: acc[mt][nt][r] = C[m = ...+quad*4+r][nk = nt*16+l16]; transposed
        // write [bh][nk][s]: 4 consecutive s per lane -> 8B stores.
        for (int mt = 0; mt < 4; mt++)
            for (int nt = 0; nt < 4; nt++) {
                int nk = nt * 16 + l16;
                float bb = bias[nk];
                int mb = m0 + wm * 64 + mt * 16 + quad * 4;
                int b = mb >> 10, s = mb & 1023;
                u16x4 o;
                for (int r = 0; r < 4; r++) o[r] = f2bf(acc[mt][nt][r] + bb);
                *(u16x4*)&Vtw[((size_t)((b << 4) + hh) * 64 + nk) * 1024 + s] = o;
            }
    }
}

// ---------------- flash attention, in-register P (R4-verified) ----------------
// grid (64 bh, 8 q-tiles) x 512 threads: 8 waves of 16 q-rows each.
// SWAPPED QK^T (mfma(K,Q)) puts P[s = nt*16+quad*4+r][q = l16] in registers;
// PV = V^T @ P^T via 16 x16-MFMAs per tile with P fed straight from VGPRs.
__global__ __launch_bounds__(512) void k_attn(
    const u16* __restrict__ Qw, const u16* __restrict__ Kw,
    const u16* __restrict__ Vtw, u16* __restrict__ Zw)
{
    __shared__ u16 Ks[2][64 * 64];
    __shared__ u16 Vs[2][64 * 64];
    int tid = threadIdx.x, w = tid >> 6, lane = tid & 63, quad = lane >> 4, l16 = lane & 15;
    int bh = blockIdx.x, q0 = blockIdx.y * 128;
    const u16* Qp = Qw + (size_t)bh * 65536;
    int rl = lane >> 3, ch = lane & 7, swch = ch ^ rl;
    const u16* Kg = Kw + (size_t)bh * 65536 + (w * 8 + rl) * 64 + swch * 8;
    const u16* Vg = Vtw + (size_t)bh * 65536 + (size_t)(w * 8 + rl) * 1024 + swch * 8;

    bf16x8 aq[2];
    for (int ks = 0; ks < 2; ks++)
        aq[ks] = *(const bf16x8*)&Qp[(size_t)(q0 + w * 16 + l16) * 64 + ks * 32 + quad * 8];

    f32x4 accT[4] = {};     // accT[db][r] = Z^T[d = db*16+quad*4+r][q = l16]
    float accs_l = 0.f;     // partial softmax denom for q = l16

#define STAGE(st, buf) { int s0_ = (st) * 64; \
    GLD16(Kg + s0_ * 64, &Ks[buf][(w * 8) * 64]); \
    GLD16(Vg + s0_, &Vs[buf][(w * 8) * 64]); }

    STAGE(0, 0);
    for (int st = 0; st < 16; st++) {
        int buf = st & 1;
        __syncthreads();
        if (st < 15) STAGE(st + 1, buf ^ 1);
        f32x4 sacc[4] = {};
        __builtin_amdgcn_s_setprio(1);
        for (int ks = 0; ks < 2; ks++) {
            int c = (ks << 2) | quad;
            for (int nt = 0; nt < 4; nt++) {
                int row = nt * 16 + l16;
                bf16x8 kf = *(bf16x8*)&Ks[buf][row * 64 + (c ^ (row & 7)) * 8];
                sacc[nt] = __builtin_amdgcn_mfma_f32_16x16x32_bf16(kf, aq[ks], sacc[nt], 0, 0, 0);
            }
        }
        __builtin_amdgcn_s_setprio(0);
        s16x4 pb[4];
        for (int nt = 0; nt < 4; nt++)
            for (int r = 0; r < 4; r++) {
                float p = __builtin_exp2f(__builtin_fmaf(sacc[nt][r], 1.44269504f, -23.0831206f));
                accs_l += p;
                union { float f; unsigned u; } cv; cv.f = p;
                pb[nt][r] = (short)((cv.u + 0x8000u) >> 16);
            }
        __builtin_amdgcn_s_setprio(1);
        for (int nt = 0; nt < 4; nt++) {
            int sc = nt * 2 + (quad >> 1);
            for (int db = 0; db < 4; db++) {
                int row = db * 16 + l16;
                s16x4 vf = *(const s16x4*)&Vs[buf][row * 64 + ((sc ^ (row & 7)) << 3) + ((quad & 1) << 2)];
                accT[db] = __builtin_amdgcn_mfma_f32_16x16x16bf16_1k(vf, pb[nt], accT[db], 0, 0, 0);
            }
        }
        __builtin_amdgcn_s_setprio(0);
    }
#undef STAGE
    accs_l += __shfl_xor(accs_l, 16, 64);
    accs_l += __shfl_xor(accs_l, 32, 64);
    float inv = 1.f / accs_l;
    int b = bh >> 4, h = bh & 15;
    int q = q0 + w * 16 + l16;
    size_t base = ((size_t)(b * 1024 + q)) * 1024 + h * 64;
    for (int db = 0; db < 4; db++) {
        u16x4 o;
        for (int r = 0; r < 4; r++) o[r] = f2bf(accT[db][r] * inv);
        *(u16x4*)&Zw[base + db * 16 + quad * 4] = o;
    }
}

// ---------------- output projection: 64x128 tiles, 512 blocks ----------------
__global__ __launch_bounds__(256) void k_oproj(
    const u16* __restrict__ Zw, const u16* __restrict__ WoT, const float* __restrict__ bo,
    const float* __restrict__ X, float* __restrict__ out)
{
    __shared__ u16 As[64 * 64];
    __shared__ u16 Bs[128 * 64];
    int tid = threadIdx.x, w = tid >> 6, lane = tid & 63, quad = lane >> 4, l16 = lane & 15;
    int wm = w & 1, wn = w >> 1;
    int m0 = blockIdx.x * 64, n0 = blockIdx.y * 128;
    int rl = lane >> 3, ch = lane & 7, swch = ch ^ rl;
    const u16* Ag = Zw + (size_t)(m0 + w * 16 + rl) * 1024 + swch * 8;
    const u16* Bg = WoT + (size_t)(n0 + w * 32 + rl) * 1024 + swch * 8;

    f32x4 acc[2][4] = {};
    for (int k0 = 0; k0 < 1024; k0 += 64) {
        for (int i = 0; i < 2; i++)
            GLD16(Ag + (size_t)i * 8 * 1024 + k0, &As[(w * 16 + i * 8) * 64]);
        for (int i = 0; i < 4; i++)
            GLD16(Bg + (size_t)i * 8 * 1024 + k0, &Bs[(w * 32 + i * 8) * 64]);
        __syncthreads();
        for (int ks = 0; ks < 2; ks++) {
            bf16x8 af[2], bf[4];
            int c = (ks << 2) | quad;
            for (int mt = 0; mt < 2; mt++) {
                int row = wm * 32 + mt * 16 + l16;
                af[mt] = *(bf16x8*)&As[row * 64 + (c ^ (row & 7)) * 8];
            }
            for (int nt = 0; nt < 4; nt++) {
                int row = wn * 64 + nt * 16 + l16;
                bf[nt] = *(bf16x8*)&Bs[row * 64 + (c ^ (row & 7)) * 8];
            }
            for (int mt = 0; mt < 2; mt++)
                for (int nt = 0; nt < 4; nt++)
                    acc[mt][nt] = __builtin_amdgcn_mfma_f32_16x16x32_bf16(af[mt], bf[nt], acc[mt][nt], 0, 0, 0);
        }
        __syncthreads();
    }
    for (int mt = 0; mt < 2; mt++)
        for (int nt = 0; nt < 4; nt++) {
            int n = n0 + wn * 64 + nt * 16 + l16;
            float bb = bo[n];
            for (int r = 0; r < 4; r++) {
                int m = m0 + wm * 32 + mt * 16 + quad * 4 + r;
                out[(size_t)m * 1024 + n] = acc[mt][nt][r] + bb + X[(size_t)m * 1024 + n];
            }
        }
}

extern "C" void kernel_launch(void* const* d_in, const int* in_sizes, int n_in,
                              void* d_out, int out_size, void* d_ws, size_t ws_size,
                              hipStream_t stream) {
    const float* X  = (const float*)d_in[0];
    const float* Wk = (const float*)d_in[1];
    const float* bk = (const float*)d_in[2];
    const float* Wq = (const float*)d_in[3];
    const float* bq = (const float*)d_in[4];
    const float* Wv = (const float*)d_in[5];
    const float* bv = (const float*)d_in[6];
    const float* Wo = (const float*)d_in[7];
    const float* bo = (const float*)d_in[8];
    u16* ws = (u16*)d_ws;
    const size_t NQ = 4u * 16u * 1024u * 64u;   // 4,194,304 elems
    u16* Qw  = ws;
    u16* Kw  = ws + NQ;
    u16* Vtw = ws + 2 * NQ;
    u16* Zw  = ws + 3 * NQ;
    u16* WT  = ws + 4 * NQ;            // [3072 n][1024 k] bf16 (K,Q,V packed)
    u16* WoT = WT + 3 * 1048576;       // [1024 n][1024 k]
    u16* Xb  = WoT + 1048576;          // X bf16
    float* outp = (float*)d_out;

    k_prep <<<5120, 256, 0, stream>>>(X, Xb, Wk, Wq, Wv, WT, Wo, WoT);
    k_qkv  <<<dim3(32, 24), 256, 0, stream>>>(Xb, WT, bk, bq, bv, Kw, Qw, Vtw);
    k_attn <<<dim3(64, 8), 512, 0, stream>>>(Qw, Kw, Vtw, Zw);
    k_oproj<<<dim3(64, 8), 256, 0, stream>>>(Zw, WoT, bo, X, outp);
}

// Round 10
// 183.931 us; speedup vs baseline: 1.2770x; 1.2770x over previous
//
#include <hip/hip_runtime.h>
#include <hip/hip_bf16.h>

typedef __bf16 bf16x8 __attribute__((ext_vector_type(8)));
typedef float f32x4 __attribute__((ext_vector_type(4)));
typedef unsigned short u16;
typedef u16 u16x4 __attribute__((ext_vector_type(4)));
typedef u16 u16x8 __attribute__((ext_vector_type(8)));
typedef short s16x4 __attribute__((ext_vector_type(4)));

#define LDA 72  // padded stride for P / transpose LDS tiles

__device__ inline u16 f2bf(float f) {
    union { float f; unsigned u; } v; v.f = f;
    unsigned r = v.u + 0x7fffu + ((v.u >> 16) & 1u);
    return (u16)(r >> 16);
}

// async global->LDS, 16B per lane; LDS dst = wave-uniform base + lane*16
#define GLD16(g, l) __builtin_amdgcn_global_load_lds( \
    (const __attribute__((address_space(1))) unsigned int*)(g), \
    (__attribute__((address_space(3))) unsigned int*)(l), 16, 0, 0)

// ---------------- prep: X convert + weight transposes ----------------
// blocks [0,4096): X fp32->bf16; [4096,4864): Wk/Wq/Wv; [4864,5120): Wo.
__global__ void k_prep(const float* __restrict__ X, u16* __restrict__ Xb,
                       const float* __restrict__ Wk, const float* __restrict__ Wq,
                       const float* __restrict__ Wv, u16* __restrict__ WT,
                       const float* __restrict__ Wo, u16* __restrict__ WoT) {
    __shared__ u16 Ls[64 * LDA];
    int u = blockIdx.x, tid = threadIdx.x;
    if (u < 4096) {
        int idx = u * 256 + tid;
        float4 v = *(const float4*)&X[(size_t)idx * 4];
        u16x4 o; o.x = f2bf(v.x); o.y = f2bf(v.y); o.z = f2bf(v.z); o.w = f2bf(v.w);
        *(u16x4*)&Xb[(size_t)idx * 4] = o;
    } else if (u < 4864) {
        int b2 = u - 4096;
        int dt = b2 & 15, h = (b2 >> 4) & 15, p = b2 >> 8;
        const float* src = (p == 0 ? Wk : p == 1 ? Wq : Wv);
        int r0 = tid >> 4, c4 = tid & 15;
        for (int j = 0; j < 4; j++) {
            int d = r0 + j * 16;
            float4 v = *(const float4*)&src[((size_t)h * 1024 + dt * 64 + d) * 64 + c4 * 4];
            u16* q = &Ls[d * LDA + c4 * 4];
            q[0] = f2bf(v.x); q[1] = f2bf(v.y); q[2] = f2bf(v.z); q[3] = f2bf(v.w);
        }
        __syncthreads();
        int nk = tid >> 2, cd = tid & 3;
        u16 tmp[16];
        for (int j = 0; j < 16; j++) tmp[j] = Ls[(cd * 16 + j) * LDA + nk];
        size_t o = ((size_t)(p * 1024 + h * 64 + nk)) * 1024 + dt * 64 + cd * 16;
        *(u16x8*)&WT[o] = *(u16x8*)&tmp[0];
        *(u16x8*)&WT[o + 8] = *(u16x8*)&tmp[8];
    } else {
        int b2 = u - 4864;
        int dt = b2 & 15, nt2 = b2 >> 4;
        int r0 = tid >> 4, c4 = tid & 15;
        for (int j = 0; j < 4; j++) {
            int d = r0 + j * 16;
            float4 v = *(const float4*)&Wo[(size_t)(dt * 64 + d) * 1024 + nt2 * 64 + c4 * 4];
            u16* q = &Ls[d * LDA + c4 * 4];
            q[0] = f2bf(v.x); q[1] = f2bf(v.y); q[2] = f2bf(v.z); q[3] = f2bf(v.w);
        }
        __syncthreads();
        int nr = tid >> 2, cd = tid & 3;
        u16 tmp[16];
        for (int j = 0; j < 16; j++) tmp[j] = Ls[(cd * 16 + j) * LDA + nr];
        size_t o = ((size_t)(nt2 * 64 + nr)) * 1024 + dt * 64 + cd * 16;
        *(u16x8*)&WoT[o] = *(u16x8*)&tmp[0];
        *(u16x8*)&WoT[o + 8] = *(u16x8*)&tmp[8];
    }
}

// ---------------- fused QKV GEMM: C[4096 m][3072 n], K=1024 ----------------
// 128x128 tile, BK=64, 4 waves 2x2, XOR-swizzled LDS, double-buffered.
// R10: COUNTED-VMCNT barriers (T4). Session evidence: time invariant to
// blocks/CU (1-3), waves (4-8), LDS read volume (R8 +50% = +-0) -> binding
// term is the per-K-step vmcnt(0) drain at __syncthreads (even R5's dbuf
// drains the JUST-issued prefetch; cover ~600cy < 300-900cy latency).
// Fix: raw s_barrier + s_waitcnt vmcnt(8): the 8 in-flight GLD16s of
// stage k+1 cross the barrier; we only wait on stage k (issued a full
// iteration ago, ~2000cy cover). Race-free: leading barrier after vmcnt(8)
// = all waves' stage-k landed; trailing barrier = all reads of buf done
// before anyone issues stage k+2 into buf. vmcnt retires oldest-first.
__global__ __launch_bounds__(256) void k_qkv(
    const u16* __restrict__ Xb, const u16* __restrict__ WT,
    const float* __restrict__ bk, const float* __restrict__ bq, const float* __restrict__ bv,
    u16* __restrict__ Kw, u16* __restrict__ Qw, u16* __restrict__ Vtw)
{
    __shared__ u16 As[2][128 * 64];
    __shared__ u16 Bs[2][128 * 64];
    int tid = threadIdx.x, w = tid >> 6, lane = tid & 63, quad = lane >> 4, l16 = lane & 15;
    int wm = w & 1, wn = w >> 1;
    int m0 = blockIdx.x * 128, n0 = blockIdx.y * 128;
    int rl = lane >> 3, ch = lane & 7, swch = ch ^ rl;
    const u16* Ag = Xb + (size_t)(m0 + w * 32 + rl) * 1024 + swch * 8;
    const u16* Bg = WT + (size_t)(n0 + w * 32 + rl) * 1024 + swch * 8;

    int hb = blockIdx.y * 2 + wn;
    int p = hb >> 4, hh = hb & 15;
    bool ct = (p < 2);                        // wave-uniform: K/Q -> transposed acc

#define QSTAGE(k0, b) for (int i = 0; i < 4; i++) { \
        GLD16(Ag + (size_t)i * 8 * 1024 + (k0), &As[b][(w * 32 + i * 8) * 64]); \
        GLD16(Bg + (size_t)i * 8 * 1024 + (k0), &Bs[b][(w * 32 + i * 8) * 64]); }
#define RBAR { __builtin_amdgcn_sched_barrier(0); __builtin_amdgcn_s_barrier(); __builtin_amdgcn_sched_barrier(0); }
#define VMCN(n) asm volatile("s_waitcnt vmcnt(" #n ")" ::: "memory")

    f32x4 acc[4][4] = {};
    QSTAGE(0, 0);
    for (int kk = 0; kk < 16; kk++) {
        int buf = kk & 1;
        if (kk < 15) { QSTAGE((kk + 1) * 64, buf ^ 1); VMCN(8); }
        else VMCN(0);
        RBAR;                                  // all waves' stage-kk landed
        for (int ks = 0; ks < 2; ks++) {
            bf16x8 af[4], bf[4];
            int c = (ks << 2) | quad;
            for (int mt = 0; mt < 4; mt++) {
                int row = wm * 64 + mt * 16 + l16;
                af[mt] = *(bf16x8*)&As[buf][row * 64 + (c ^ (row & 7)) * 8];
            }
            for (int nt = 0; nt < 4; nt++) {
                int row = wn * 64 + nt * 16 + l16;
                bf[nt] = *(bf16x8*)&Bs[buf][row * 64 + (c ^ (row & 7)) * 8];
            }
            if (ct) {
                for (int mt = 0; mt < 4; mt++)
                    for (int nt = 0; nt < 4; nt++)
                        acc[mt][nt] = __builtin_amdgcn_mfma_f32_16x16x32_bf16(bf[nt], af[mt], acc[mt][nt], 0, 0, 0);
            } else {
                for (int mt = 0; mt < 4; mt++)
                    for (int nt = 0; nt < 4; nt++)
                        acc[mt][nt] = __builtin_amdgcn_mfma_f32_16x16x32_bf16(af[mt], bf[nt], acc[mt][nt], 0, 0, 0);
            }
        }
        RBAR;                                  // reads of buf done before stage kk+2 -> buf
    }
#undef QSTAGE
#undef RBAR
#undef VMCN
    const float* bias = (p == 0 ? bk : p == 1 ? bq : bv) + hh * 64;
    if (ct) {
        // acc[mt][nt][r] = C[m = m0+wm*64+mt*16+l16][nk = nt*16+quad*4+r]
        u16* dst = (p == 0) ? Kw : Qw;
        float sc = (p == 0) ? 0.125f : 1.0f;   // fold 1/sqrt(64) into K
        for (int mt = 0; mt < 4; mt++) {
            int m = m0 + wm * 64 + mt * 16 + l16;
            int b = m >> 10, s = m & 1023;
            size_t base = ((size_t)((b << 4) + hh) * 1024 + s) * 64;
            for (int nt = 0; nt < 4; nt++) {
                float4 bb = *(const float4*)&bias[nt * 16 + quad * 4];
                u16x4 o;
                o[0] = f2bf((acc[mt][nt][0] + bb.x) * sc);
                o[1] = f2bf((acc[mt][nt][1] + bb.y) * sc);
                o[2] = f2bf((acc[mt][nt][2] + bb.z) * sc);
                o[3] = f2bf((acc[mt][nt][3] + bb.w) * sc);
                *(u16x4*)&dst[base + nt * 16 + quad * 4] = o;
            }
        }
    } else {
        // V: acc[mt][nt][r] = C[m = ...+quad*4+r][nk = nt*16+l16]; transposed
        // write [bh][nk][s]: 4 consecutive s per lane -> 8B stores.
        for (int mt = 0; mt < 4; mt++)
            for (int nt = 0; nt < 4; nt++) {
                int nk = nt * 16 + l16;
                float bb = bias[nk];
                int mb = m0 + wm * 64 + mt * 16 + quad * 4;
                int b = mb >> 10, s = mb & 1023;
                u16x4 o;
                for (int r = 0; r < 4; r++) o[r] = f2bf(acc[mt][nt][r] + bb);
                *(u16x4*)&Vtw[((size_t)((b << 4) + hh) * 64 + nk) * 1024 + s] = o;
            }
    }
}

// ---------------- flash attention, in-register P (R4-verified) ----------------
// grid (64 bh, 8 q-tiles) x 512 threads: 8 waves of 16 q-rows each.
// SWAPPED QK^T (mfma(K,Q)) puts P[s = nt*16+quad*4+r][q = l16] in registers;
// PV = V^T @ P^T via 16 x16-MFMAs per tile with P fed straight from VGPRs.
__global__ __launch_bounds__(512) void k_attn(
    const u16* __restrict__ Qw, const u16* __restrict__ Kw,
    const u16* __restrict__ Vtw, u16* __restrict__ Zw)
{
    __shared__ u16 Ks[2][64 * 64];
    __shared__ u16 Vs[2][64 * 64];
    int tid = threadIdx.x, w = tid >> 6, lane = tid & 63, quad = lane >> 4, l16 = lane & 15;
    int bh = blockIdx.x, q0 = blockIdx.y * 128;
    const u16* Qp = Qw + (size_t)bh * 65536;
    int rl = lane >> 3, ch = lane & 7, swch = ch ^ rl;
    const u16* Kg = Kw + (size_t)bh * 65536 + (w * 8 + rl) * 64 + swch * 8;
    const u16* Vg = Vtw + (size_t)bh * 65536 + (size_t)(w * 8 + rl) * 1024 + swch * 8;

    bf16x8 aq[2];
    for (int ks = 0; ks < 2; ks++)
        aq[ks] = *(const bf16x8*)&Qp[(size_t)(q0 + w * 16 + l16) * 64 + ks * 32 + quad * 8];

    f32x4 accT[4] = {};     // accT[db][r] = Z^T[d = db*16+quad*4+r][q = l16]
    float accs_l = 0.f;     // partial softmax denom for q = l16

#define STAGE(st, buf) { int s0_ = (st) * 64; \
    GLD16(Kg + s0_ * 64, &Ks[buf][(w * 8) * 64]); \
    GLD16(Vg + s0_, &Vs[buf][(w * 8) * 64]); }

    STAGE(0, 0);
    for (int st = 0; st < 16; st++) {
        int buf = st & 1;
        __syncthreads();
        if (st < 15) STAGE(st + 1, buf ^ 1);
        f32x4 sacc[4] = {};
        __builtin_amdgcn_s_setprio(1);
        for (int ks = 0; ks < 2; ks++) {
            int c = (ks << 2) | quad;
            for (int nt = 0; nt < 4; nt++) {
                int row = nt * 16 + l16;
                bf16x8 kf = *(bf16x8*)&Ks[buf][row * 64 + (c ^ (row & 7)) * 8];
                sacc[nt] = __builtin_amdgcn_mfma_f32_16x16x32_bf16(kf, aq[ks], sacc[nt], 0, 0, 0);
            }
        }
        __builtin_amdgcn_s_setprio(0);
        s16x4 pb[4];
        for (int nt = 0; nt < 4; nt++)
            for (int r = 0; r < 4; r++) {
                float p = __builtin_exp2f(__builtin_fmaf(sacc[nt][r], 1.44269504f, -23.0831206f));
                accs_l += p;
                union { float f; unsigned u; } cv; cv.f = p;
                pb[nt][r] = (short)((cv.u + 0x8000u) >> 16);
            }
        __builtin_amdgcn_s_setprio(1);
        for (int nt = 0; nt < 4; nt++) {
            int sc = nt * 2 + (quad >> 1);
            for (int db = 0; db < 4; db++) {
                int row = db * 16 + l16;
                s16x4 vf = *(const s16x4*)&Vs[buf][row * 64 + ((sc ^ (row & 7)) << 3) + ((quad & 1) << 2)];
                accT[db] = __builtin_amdgcn_mfma_f32_16x16x16bf16_1k(vf, pb[nt], accT[db], 0, 0, 0);
            }
        }
        __builtin_amdgcn_s_setprio(0);
    }
#undef STAGE
    accs_l += __shfl_xor(accs_l, 16, 64);
    accs_l += __shfl_xor(accs_l, 32, 64);
    float inv = 1.f / accs_l;
    int b = bh >> 4, h = bh & 15;
    int q = q0 + w * 16 + l16;
    size_t base = ((size_t)(b * 1024 + q)) * 1024 + h * 64;
    for (int db = 0; db < 4; db++) {
        u16x4 o;
        for (int r = 0; r < 4; r++) o[r] = f2bf(accT[db][r] * inv);
        *(u16x4*)&Zw[base + db * 16 + quad * 4] = o;
    }
}

// ---------------- output projection: 64x128 tiles, 512 blocks ----------------
__global__ __launch_bounds__(256) void k_oproj(
    const u16* __restrict__ Zw, const u16* __restrict__ WoT, const float* __restrict__ bo,
    const float* __restrict__ X, float* __restrict__ out)
{
    __shared__ u16 As[64 * 64];
    __shared__ u16 Bs[128 * 64];
    int tid = threadIdx.x, w = tid >> 6, lane = tid & 63, quad = lane >> 4, l16 = lane & 15;
    int wm = w & 1, wn = w >> 1;
    int m0 = blockIdx.x * 64, n0 = blockIdx.y * 128;
    int rl = lane >> 3, ch = lane & 7, swch = ch ^ rl;
    const u16* Ag = Zw + (size_t)(m0 + w * 16 + rl) * 1024 + swch * 8;
    const u16* Bg = WoT + (size_t)(n0 + w * 32 + rl) * 1024 + swch * 8;

    f32x4 acc[2][4] = {};
    for (int k0 = 0; k0 < 1024; k0 += 64) {
        for (int i = 0; i < 2; i++)
            GLD16(Ag + (size_t)i * 8 * 1024 + k0, &As[(w * 16 + i * 8) * 64]);
        for (int i = 0; i < 4; i++)
            GLD16(Bg + (size_t)i * 8 * 1024 + k0, &Bs[(w * 32 + i * 8) * 64]);
        __syncthreads();
        for (int ks = 0; ks < 2; ks++) {
            bf16x8 af[2], bf[4];
            int c = (ks << 2) | quad;
            for (int mt = 0; mt < 2; mt++) {
                int row = wm * 32 + mt * 16 + l16;
                af[mt] = *(bf16x8*)&As[row * 64 + (c ^ (row & 7)) * 8];
            }
            for (int nt = 0; nt < 4; nt++) {
                int row = wn * 64 + nt * 16 + l16;
                bf[nt] = *(bf16x8*)&Bs[row * 64 + (c ^ (row & 7)) * 8];
            }
            for (int mt = 0; mt < 2; mt++)
                for (int nt = 0; nt < 4; nt++)
                    acc[mt][nt] = __builtin_amdgcn_mfma_f32_16x16x32_bf16(af[mt], bf[nt], acc[mt][nt], 0, 0, 0);
        }
        __syncthreads();
    }
    for (int mt = 0; mt < 2; mt++)
        for (int nt = 0; nt < 4; nt++) {
            int n = n0 + wn * 64 + nt * 16 + l16;
            float bb = bo[n];
            for (int r = 0; r < 4; r++) {
                int m = m0 + wm * 32 + mt * 16 + quad * 4 + r;
                out[(size_t)m * 1024 + n] = acc[mt][nt][r] + bb + X[(size_t)m * 1024 + n];
            }
        }
}

extern "C" void kernel_launch(void* const* d_in, const int* in_sizes, int n_in,
                              void* d_out, int out_size, void* d_ws, size_t ws_size,
                              hipStream_t stream) {
    const float* X  = (const float*)d_in[0];
    const float* Wk = (const float*)d_in[1];
    const float* bk = (const float*)d_in[2];
    const float* Wq = (const float*)d_in[3];
    const float* bq = (const float*)d_in[4];
    const float* Wv = (const float*)d_in[5];
    const float* bv = (const float*)d_in[6];
    const float* Wo = (const float*)d_in[7];
    const float* bo = (const float*)d_in[8];
    u16* ws = (u16*)d_ws;
    const size_t NQ = 4u * 16u * 1024u * 64u;   // 4,194,304 elems
    u16* Qw  = ws;
    u16* Kw  = ws + NQ;
    u16* Vtw = ws + 2 * NQ;
    u16* Zw  = ws + 3 * NQ;
    u16* WT  = ws + 4 * NQ;            // [3072 n][1024 k] bf16 (K,Q,V packed)
    u16* WoT = WT + 3 * 1048576;       // [1024 n][1024 k]
    u16* Xb  = WoT + 1048576;          // X bf16
    float* outp = (float*)d_out;

    k_prep <<<5120, 256, 0, stream>>>(X, Xb, Wk, Wq, Wv, WT, Wo, WoT);
    k_qkv  <<<dim3(32, 24), 256, 0, stream>>>(Xb, WT, bk, bq, bv, Kw, Qw, Vtw);
    k_attn <<<dim3(64, 8), 512, 0, stream>>>(Qw, Kw, Vtw, Zw);
    k_oproj<<<dim3(64, 8), 256, 0, stream>>>(Zw, WoT, bo, X, outp);
}